// Round 8
// baseline (777.765 us; speedup 1.0000x reference)
//
#include <hip/hip_runtime.h>
#include <cstdint>

// ---------------- problem constants ----------------
static constexpr long long Bb = 16, Nn = 1024, FE = 512; // heads=2, g=512
static constexpr long long BN = Bb * Nn;        // 16384
static constexpr long long E1e = BN * FE;       // elems of [B,N,FE] (8388608)
static constexpr long long E2n = BN * Nn;       // elems of [B,N,N]

// ---------------- workspace layout (bytes) ----------------
static constexpr long long O_WT  = 0;                      // 6x 512x512 bf16 (plain cast W1..W6)
static constexpr long long SZ_W512 = FE * FE * 2;
static constexpr long long O_WQT = O_WT + 6 * SZ_W512;     // 1024-transposed weights
static constexpr long long SZ_W1K = Nn * Nn * 2;
static constexpr long long O_WKT = O_WQT + SZ_W1K;
static constexpr long long O_WVT = O_WKT + SZ_W1K;
static constexpr long long O_F1T = O_WVT + SZ_W1K;
static constexpr long long O_F2T = O_F1T + SZ_W1K;
static constexpr long long O_SLOTS = O_F2T + SZ_W1K;       // 13,631,488
static constexpr long long SLOT = E2n * 2;                 // 32 MiB
static constexpr long long O_S0 = O_SLOTS;                 // P planes -> Q -> o
static constexpr long long O_S1 = O_S0 + SLOT;             // P tail -> K -> x
static constexpr long long O_S2 = O_S1 + SLOT;             // Gt -> aqq -> h
static constexpr long long O_E0 = O_S2 + SLOT;             // F planes -> asq -> scores h1
static constexpr long long O_E1 = O_E0 + SLOT;             // Fq plane -> Vt
static constexpr long long O_E2 = O_E1 + SLOT;             // ass -> scores h0
static constexpr long long WS_NEED = O_E2 + SLOT;          // ~205 MiB
// phase-A temporaries:
static constexpr long long O_FB = O_E0;                    // F planes [Fms|Fs|Fq], stride E1e elems
static constexpr long long O_GT = O_S2;                    // 3x 512x512 Gt planes (dead after P)

// ---------------- helpers ----------------
typedef __attribute__((ext_vector_type(8))) short short8;
typedef __attribute__((ext_vector_type(16))) float f32x16;

static __device__ __forceinline__ unsigned short f2bf(float f) {
  union { float f; unsigned u; } x; x.f = f;
  unsigned r = x.u + 0x7FFFu + ((x.u >> 16) & 1u);
  return (unsigned short)(r >> 16);
}
static __device__ __forceinline__ float bf2f(unsigned short h) {
  union { unsigned u; float f; } x; x.u = ((unsigned)h) << 16; return x.f;
}
static __device__ __forceinline__ void gload16(const void* g, void* l) {
  __builtin_amdgcn_global_load_lds(
      (const __attribute__((address_space(1))) unsigned int*)g,
      (__attribute__((address_space(3))) unsigned int*)l, 16, 0, 0);
}

// ---------------- bf16 NT GEMM, 256x256 tile, ring-4, pipelined 32x32 MFMA ----
// C[m,n] = sum_k A[m,k]*B[n,k].  8 waves (2M x 4N), per-wave output 128x64.
// MFMA 32x32x16 bf16; BK=32 per K-step = 2 k-slices of 16.
// Cross-slice software pipeline (reads feed the NEXT slice, so ds_read and
// MFMA overlap within each wave):
//   iter t:  READ(t,ks1)->F1  ||  MFMA8(F0)
//            STAGE(t+3); vmcnt(8); lgkmcnt(0); barrier
//            READ(t+1,ks0)->F0 || MFMA8(F1)
// One barrier per K-step.  vmcnt(8): 12 outstanding -> retires st(t+1).
// lgkmcnt(0)+barrier closes the buf[t-1] anti-dep before STAGE(t+3).
// Tails drain vmcnt 8->4->0.
// LDS layout (R8 change, replaces XOR swizzle): k-major chunk layout.
// Each 8-KiB half-tile (128 rows x 32 k-elems) is stored [kp][row][kl]:
//   byte addr = kp*4096 + row*32 + kl*16   (k-slot = kp*2+kl, 8 elems each)
// Slice ks of fragment mi then reads rows mi*32+l31, kl=lh: a DENSE 1024-B
// region per ds_read_b128 instruction -> 0 bank conflicts (R1-verified
// pattern; R7's XOR slot swizzle measured 6.3e6 conflicts on the 32-row
// column-slice reads).  Realized per rule "both-sides-or-neither": linear
// gload_lds dest + permuted GLOBAL source: thread tid holds chunk
// (kp=tid>>8, r=(tid>>1)&127, kl=tid&1) -> source row r, k-elems (kp*2+kl)*8.
// C/D layout (m74/m101): col = lane&31, row = (reg&3)+8*(reg>>2)+4*(lane>>5).
// XCD swizzle: bijective m204 variant.  Batch z: z1=z&15, z2=z>>4.
// EP: 1 = bf16 out, 2 = bf16 relu out, 3 = f32 out + bf16 residual R.
template <int EP>
__global__ __launch_bounds__(512, 2) void gemm256(
    const unsigned short* __restrict__ A, long long sA, long long hA, int lda,
    const unsigned short* __restrict__ B, long long sB, long long hB, int ldb,
    void* __restrict__ Cv, long long sC, long long hC, int ldc,
    const void* __restrict__ Rv, long long sR, int K) {
  extern __shared__ unsigned short lds[];
  const int tid = threadIdx.x;
  const int lane = tid & 63;
  const int wave = tid >> 6;
  const int wm = wave >> 2, wn = wave & 3;
  const int l31 = lane & 31, lh = lane >> 5;

  // bijective XCD swizzle (m204): works for any nwg
  const int gx = gridDim.x;
  const int nxy = gx * gridDim.y;
  const int nwg = nxy * gridDim.z;
  int wg = blockIdx.x + gx * blockIdx.y + nxy * blockIdx.z;
  {
    const int q = nwg >> 3, r = nwg & 7;
    const int xcd = wg & 7, blk = wg >> 3;
    wg = (xcd < r ? xcd * (q + 1) : r * (q + 1) + (xcd - r) * q) + blk;
  }
  const int bz = wg / nxy;
  const int rem = wg - bz * nxy;
  const int by = rem / gx;
  const int bx = rem - by * gx;
  const int z1 = bz & 15, z2 = bz >> 4;

  const long long bm = (long long)bx * 256;
  const long long bn = (long long)by * 256;
  const unsigned short* Ab = A + z1 * sA + z2 * hA + bm * lda;
  const unsigned short* Bp = B + z1 * sB + z2 * hB + bn * ldb;

  // staging (k-major chunk layout): thread tid -> chunk (kp,r,kl); source
  // row r (+0/+128), k-elems (kp*2+kl)*8; dest is linear tid*16B.
  const int srow = (tid >> 1) & 127;
  const int scol = (((tid >> 8) & 1) * 2 + (tid & 1)) * 8;
  unsigned short* ldst = lds + tid * 8;
  auto STAGE = [&](int tt) {
    unsigned short* d = ldst + (tt & 3) * 16384;
    const long long ko = (long long)tt * 32 + scol;
    gload16(Ab + (long long)srow * lda + ko, d);
    gload16(Ab + (long long)(srow + 128) * lda + ko, d + 4096);
    gload16(Bp + (long long)srow * ldb + ko, d + 8192);
    gload16(Bp + (long long)(srow + 128) * ldb + ko, d + 12288);
  };

  // fragment read offsets (elems).  Slice ks, fragment mi/ni reads the dense
  // region: half_base + ks*2048 + (frag*32 + l31)*16 + lh*8.
  const int aoff0 = wm * 4096 + l31 * 16 + lh * 8;            // ks=0, + mi*512
  const int aoff1 = aoff0 + 2048;                              // ks=1
  const int boff0 = 8192 + (wn >> 1) * 4096 + ((wn & 1) * 64 + l31) * 16 + lh * 8;
  const int boff1 = boff0 + 2048;

  f32x16 acc[4][2];
#pragma unroll
  for (int mi = 0; mi < 4; ++mi)
#pragma unroll
    for (int ni = 0; ni < 2; ++ni)
      acc[mi][ni] = (f32x16){0.f, 0.f, 0.f, 0.f, 0.f, 0.f, 0.f, 0.f,
                             0.f, 0.f, 0.f, 0.f, 0.f, 0.f, 0.f, 0.f};

  short8 a0[4], b0[2], a1[4], b1[2];
  auto READ0 = [&](int tt) {  // slice ks=0 -> F0 (6 ds_read_b128, all dense)
    const unsigned short* lb = lds + (tt & 3) * 16384;
#pragma unroll
    for (int mi = 0; mi < 4; ++mi) a0[mi] = *(const short8*)&lb[aoff0 + mi * 512];
    b0[0] = *(const short8*)&lb[boff0];
    b0[1] = *(const short8*)&lb[boff0 + 512];
  };
  auto READ1 = [&](int tt) {  // slice ks=1 -> F1
    const unsigned short* lb = lds + (tt & 3) * 16384;
#pragma unroll
    for (int mi = 0; mi < 4; ++mi) a1[mi] = *(const short8*)&lb[aoff1 + mi * 512];
    b1[0] = *(const short8*)&lb[boff1];
    b1[1] = *(const short8*)&lb[boff1 + 512];
  };
  auto MFMA8 = [&](const short8* a, const short8* b) {  // 8 independent MFMA
    __builtin_amdgcn_s_setprio(1);
#pragma unroll
    for (int mi = 0; mi < 4; ++mi)
#pragma unroll
      for (int ni = 0; ni < 2; ++ni)
        acc[mi][ni] = __builtin_amdgcn_mfma_f32_32x32x16_bf16(a[mi], b[ni], acc[mi][ni], 0, 0, 0);
    __builtin_amdgcn_s_setprio(0);
  };

  const int nt = K >> 5;   // >= 16 here
  STAGE(0); STAGE(1); STAGE(2);
  asm volatile("s_waitcnt vmcnt(8)" ::: "memory");   // st(0) retired
  __builtin_amdgcn_s_barrier();                      // buf0 globally ready
  READ0(0);
  int t = 0;
  for (; t < nt - 3; ++t) {
    READ1(t);                 // F1 reads overlap F0 MFMAs (no dependence)
    MFMA8(a0, b0);
    STAGE(t + 3);
    asm volatile("s_waitcnt vmcnt(8)" ::: "memory");  // st(t+1) retired
    asm volatile("s_waitcnt lgkmcnt(0)" ::: "memory");// reads of buf[t-1] done
    __builtin_amdgcn_s_barrier();                     // buf[t+1] globally ready
    READ0(t + 1);             // F0 reads overlap F1 MFMAs
    MFMA8(a1, b1);
  }
  // ---- tail t = nt-3 ----
  READ1(t);
  MFMA8(a0, b0);
  asm volatile("s_waitcnt vmcnt(4)" ::: "memory");
  asm volatile("s_waitcnt lgkmcnt(0)" ::: "memory");
  __builtin_amdgcn_s_barrier();
  READ0(t + 1);
  MFMA8(a1, b1);
  ++t;
  // ---- tail t = nt-2 ----
  READ1(t);
  MFMA8(a0, b0);
  asm volatile("s_waitcnt vmcnt(0)" ::: "memory");
  asm volatile("s_waitcnt lgkmcnt(0)" ::: "memory");
  __builtin_amdgcn_s_barrier();
  READ0(t + 1);
  MFMA8(a1, b1);
  ++t;
  // ---- tail t = nt-1 ----
  READ1(t);
  MFMA8(a0, b0);
  MFMA8(a1, b1);

  // epilogue: 32x32 C/D map col=lane&31, row=(reg&3)+8*(reg>>2)+4*lh (m74/m101)
  const long long cm = bm + wm * 128, cn = bn + wn * 64;
  const long long cz = z1 * sC + z2 * hC;
#pragma unroll
  for (int mi = 0; mi < 4; ++mi) {
#pragma unroll
    for (int ni = 0; ni < 2; ++ni) {
      long long col = cn + ni * 32 + l31;
#pragma unroll
      for (int reg = 0; reg < 16; ++reg) {
        long long row = cm + mi * 32 + (reg & 3) + 8 * (reg >> 2) + 4 * lh;
        float v = acc[mi][ni][reg];
        long long idx = cz + row * ldc + col;
        if (EP == 1) ((unsigned short*)Cv)[idx] = f2bf(v);
        else if (EP == 2) ((unsigned short*)Cv)[idx] = f2bf(v > 0.f ? v : 0.f);
        else {
          float rr = bf2f(((const unsigned short*)Rv)[z1 * sR + row * ldc + col]);
          ((float*)Cv)[idx] = v + rr;
        }
      }
    }
  }
}

// ---------------- merged cast f32 -> bf16, 3 planes per dispatch ----------------
__global__ __launch_bounds__(256) void cast3_k(const float* __restrict__ i0,
                                               const float* __restrict__ i1,
                                               const float* __restrict__ i2,
                                               unsigned short* o0, unsigned short* o1,
                                               unsigned short* o2) {
  const float* in = (blockIdx.y == 0) ? i0 : (blockIdx.y == 1) ? i1 : i2;
  unsigned short* out = (blockIdx.y == 0) ? o0 : (blockIdx.y == 1) ? o1 : o2;
  long long i = (long long)blockIdx.x * 256 + threadIdx.x;
  float4 v = ((const float4*)in)[i];
  ushort4 o; o.x = f2bf(v.x); o.y = f2bf(v.y); o.z = f2bf(v.z); o.w = f2bf(v.w);
  ((ushort4*)out)[i] = o;
}

// ---------------- merged transpose+cast: z selects source ----------------
__global__ __launch_bounds__(256) void tcast6_k(const float* p0, const float* p1,
                                                const float* p2, const float* p3,
                                                const float* p4, const float* p5,
                                                unsigned short* outb, int rows, int cols) {
  const float* src[6] = {p0, p1, p2, p3, p4, p5};
  const float* in = src[blockIdx.z];
  unsigned short* out = outb + (long long)blockIdx.z * rows * cols;
  __shared__ float t[32][33];
  const int c0 = blockIdx.x * 32, r0 = blockIdx.y * 32;
  const int tx = threadIdx.x, ty = threadIdx.y; // block (32,8)
#pragma unroll
  for (int i = 0; i < 4; ++i) {
    int r = r0 + ty + i * 8;
    t[ty + i * 8][tx] = in[(long long)r * cols + c0 + tx];
  }
  __syncthreads();
#pragma unroll
  for (int i = 0; i < 4; ++i) {
    int c = c0 + ty + i * 8;
    out[(long long)c * rows + r0 + tx] = f2bf(t[tx][ty + i * 8]);
  }
}

// ---------------- in-place row softmax over bf16 (1024 cols), scaled ----------------
__global__ __launch_bounds__(256) void softmax_bf(unsigned short* __restrict__ S, float scale) {
  __shared__ float redA[4], redB[4];
  const long long row = blockIdx.x;
  const int t = threadIdx.x, wave = t >> 6, lane = t & 63;
  ushort4 u = ((ushort4*)(S + row * 1024))[t];
  float v0 = bf2f(u.x) * scale, v1 = bf2f(u.y) * scale, v2 = bf2f(u.z) * scale, v3 = bf2f(u.w) * scale;
  float m = fmaxf(fmaxf(v0, v1), fmaxf(v2, v3));
#pragma unroll
  for (int o = 32; o; o >>= 1) m = fmaxf(m, __shfl_down(m, o));
  if (lane == 0) redA[wave] = m;
  __syncthreads();
  m = fmaxf(fmaxf(redA[0], redA[1]), fmaxf(redA[2], redA[3]));
  float e0 = __expf(v0 - m), e1 = __expf(v1 - m), e2 = __expf(v2 - m), e3 = __expf(v3 - m);
  float s = e0 + e1 + e2 + e3;
#pragma unroll
  for (int o = 32; o; o >>= 1) s += __shfl_down(s, o);
  if (lane == 0) redB[wave] = s;
  __syncthreads();
  s = redB[0] + redB[1] + redB[2] + redB[3];
  float inv = 1.f / s;
  ushort4 ob; ob.x = f2bf(e0 * inv); ob.y = f2bf(e1 * inv); ob.z = f2bf(e2 * inv); ob.w = f2bf(e3 * inv);
  ((ushort4*)(S + row * 1024))[t] = ob;
}

// ---------------- LN1: x = LN(o + aqq)*g + b -> bf16 ----------------
__global__ __launch_bounds__(256) void ln1_k(const unsigned short* __restrict__ O,
                                             const unsigned short* __restrict__ Aq,
                                             const float* __restrict__ g, const float* __restrict__ b,
                                             unsigned short* __restrict__ xb) {
  __shared__ float redA[4], redB[4];
  const long long row = blockIdx.x;
  const int t = threadIdx.x, wave = t >> 6, lane = t & 63;
  ushort4 ou = ((const ushort4*)(O + row * 1024))[t];
  ushort4 au = ((const ushort4*)(Aq + row * 1024))[t];
  float v0 = bf2f(ou.x) + bf2f(au.x), v1 = bf2f(ou.y) + bf2f(au.y);
  float v2 = bf2f(ou.z) + bf2f(au.z), v3 = bf2f(ou.w) + bf2f(au.w);
  float s = v0 + v1 + v2 + v3;
  float q = v0 * v0 + v1 * v1 + v2 * v2 + v3 * v3;
#pragma unroll
  for (int o = 32; o; o >>= 1) { s += __shfl_down(s, o); q += __shfl_down(q, o); }
  if (lane == 0) { redA[wave] = s; redB[wave] = q; }
  __syncthreads();
  float S = redA[0] + redA[1] + redA[2] + redA[3];
  float Q = redB[0] + redB[1] + redB[2] + redB[3];
  float mu = S * (1.f / 1024.f);
  float var = Q * (1.f / 1024.f) - mu * mu;
  float rs = rsqrtf(var + 1e-5f);
  float4 gg = ((const float4*)g)[t], bbv = ((const float4*)b)[t];
  ushort4 ob;
  ob.x = f2bf((v0 - mu) * rs * gg.x + bbv.x);
  ob.y = f2bf((v1 - mu) * rs * gg.y + bbv.y);
  ob.z = f2bf((v2 - mu) * rs * gg.z + bbv.z);
  ob.w = f2bf((v3 - mu) * rs * gg.w + bbv.w);
  ((ushort4*)(xb + row * 1024))[t] = ob;
}

// ---------------- LN2: y = LN(y0)*g + b, f32 in-place safe ----------------
__global__ __launch_bounds__(256) void ln2_k(const float* __restrict__ Y,
                                             const float* __restrict__ g, const float* __restrict__ b,
                                             float* __restrict__ out, float eps) {
  __shared__ float redA[4], redB[4];
  const long long row = blockIdx.x;
  const int t = threadIdx.x, wave = t >> 6, lane = t & 63;
  float4 v = ((const float4*)(Y + row * 1024))[t];
  float s = v.x + v.y + v.z + v.w;
  float q = v.x * v.x + v.y * v.y + v.z * v.z + v.w * v.w;
#pragma unroll
  for (int o = 32; o; o >>= 1) { s += __shfl_down(s, o); q += __shfl_down(q, o); }
  if (lane == 0) { redA[wave] = s; redB[wave] = q; }
  __syncthreads();
  float S = redA[0] + redA[1] + redA[2] + redA[3];
  float Q = redB[0] + redB[1] + redB[2] + redB[3];
  float mu = S * (1.f / 1024.f);
  float var = Q * (1.f / 1024.f) - mu * mu;
  float rs = rsqrtf(var + eps);
  float4 gg = ((const float4*)g)[t], bbv = ((const float4*)b)[t];
  float4 o;
  o.x = (v.x - mu) * rs * gg.x + bbv.x;
  o.y = (v.y - mu) * rs * gg.y + bbv.y;
  o.z = (v.z - mu) * rs * gg.z + bbv.z;
  o.w = (v.w - mu) * rs * gg.w + bbv.w;
  ((float4*)(out + row * 1024))[t] = o;
}

// ---------------- launcher ----------------
extern "C" void kernel_launch(void* const* d_in, const int* in_sizes, int n_in,
                              void* d_out, int out_size, void* d_ws, size_t ws_size,
                              hipStream_t stream) {
  (void)in_sizes; (void)n_in; (void)out_size;
  if (ws_size < (size_t)WS_NEED) return; // diagnostic guard (absmax ~7.09 if hit)

  static int attr_once = []() {
    (void)hipFuncSetAttribute(reinterpret_cast<const void*>(&gemm256<1>),
                              hipFuncAttributeMaxDynamicSharedMemorySize, 131072);
    (void)hipFuncSetAttribute(reinterpret_cast<const void*>(&gemm256<2>),
                              hipFuncAttributeMaxDynamicSharedMemorySize, 131072);
    (void)hipFuncSetAttribute(reinterpret_cast<const void*>(&gemm256<3>),
                              hipFuncAttributeMaxDynamicSharedMemorySize, 131072);
    return 0;
  }();
  (void)attr_once;

  const float* Fs  = (const float*)d_in[0];
  const float* Fq  = (const float*)d_in[1];
  const float* Fms = (const float*)d_in[2];
  const float* Wm[6] = {(const float*)d_in[4], (const float*)d_in[5], (const float*)d_in[6],
                        (const float*)d_in[7], (const float*)d_in[8], (const float*)d_in[9]};
  const float* Wq = (const float*)d_in[10];
  const float* Wk = (const float*)d_in[11];
  const float* Wv = (const float*)d_in[12];
  const float* ln_g = (const float*)d_in[13];
  const float* ln_b = (const float*)d_in[14];
  const float* fw1 = (const float*)d_in[15];
  const float* fw2 = (const float*)d_in[16];
  const float* fg = (const float*)d_in[17];
  const float* fb = (const float*)d_in[18];
  float* out = (float*)d_out;
  uint8_t* ws = (uint8_t*)d_ws;
  auto U16 = [&](long long off) { return (unsigned short*)(ws + off); };

  const float inv_sqrt512 = 0.04419417382415922f; // 1/sqrt(512) == 1/sqrt(g)
  dim3 blk(256);

  auto gemm = [&](int ep, const unsigned short* A, long long sA, long long hA, int lda,
                  const unsigned short* B, long long sB, long long hB, int ldb,
                  void* C, long long sC, long long hC, int ldc, const void* R, long long sR,
                  int M, int N, int K, int batch) {
    dim3 g(M / 256, N / 256, batch);
    dim3 b(512);
    switch (ep) {
      case 1: gemm256<1><<<g, b, 131072, stream>>>(A, sA, hA, lda, B, sB, hB, ldb, C, sC, hC, ldc, R, sR, K); break;
      case 2: gemm256<2><<<g, b, 131072, stream>>>(A, sA, hA, lda, B, sB, hB, ldb, C, sC, hC, ldc, R, sR, K); break;
      default: gemm256<3><<<g, b, 131072, stream>>>(A, sA, hA, lda, B, sB, hB, ldb, C, sC, hC, ldc, R, sR, K); break;
    }
  };

  // ---- weight prep ----
  // plain cast W1..W6 -> bf16 planes at O_WT (262144 elems each)
  unsigned short* Wc = U16(O_WT);
  cast3_k<<<dim3(256, 3), blk, 0, stream>>>(Wm[0], Wm[1], Wm[2], Wc, Wc + 262144, Wc + 2 * 262144);
  cast3_k<<<dim3(256, 3), blk, 0, stream>>>(Wm[3], Wm[4], Wm[5], Wc + 3 * 262144, Wc + 4 * 262144, Wc + 5 * 262144);
  // transpose+cast 1024 weights (Wq,Wk,Wv,ffn_w1,ffn_w2)
  tcast6_k<<<dim3(32, 32, 5), dim3(32, 8), 0, stream>>>(
      Wq, Wk, Wv, fw1, fw2, fw2 /*unused*/, U16(O_WQT), 1024, 1024);
  // input casts -> F planes [Fms|Fs|Fq] at O_FB (stride E1e elems)
  unsigned short* FB = U16(O_FB);
  cast3_k<<<dim3(E1e / 4 / 256, 3), blk, 0, stream>>>(
      Fms, Fs, Fq, FB, FB + E1e, FB + 2 * E1e);

  // ---- Phase A: affinities via fused weight products ----
  // Gt planes [ss,sq,qq] at O_GT: Gt_xy = NT(W_even, W_odd)  (Gt = (Wa Wb^T)^T)
  gemm(1, Wc + 262144, 524288, 0, 512, Wc, 524288, 0, 512,
       U16(O_GT), 262144, 0, 512, nullptr, 0, 512, 512, 512, 3);
  // P planes = NT(F, Gt) -> S0 (stride E1e): P_ss=Fms@G_ss, P_sq=Fs@G_sq, P_qq=Fq@G_qq
  gemm(1, FB, E1e, 0, 512, U16(O_GT), 262144, 0, 512,
       U16(O_S0), E1e, 0, 512, nullptr, 0, (int)BN, 512, 512, 3);
  // scores_ss = NT(P_ss, Fms) batch16 -> E2
  gemm(1, U16(O_S0), Nn * 512, 0, 512, FB, Nn * 512, 0, 512,
       U16(O_E2), Nn * Nn, 0, 1024, nullptr, 0, 1024, 1024, 512, (int)Bb);
  // scores_sq/qq = NT(P_sq|P_qq, Fq) batch32: z2=0 -> sq@E0, z2=1 -> qq@S2
  gemm(1, U16(O_S0) + E1e, Nn * 512, E1e, 512, FB + 2 * E1e, Nn * 512, 0, 512,
       U16(O_E0), Nn * Nn, -(long long)E2n, 1024, nullptr, 0, 1024, 1024, 512, 32);
  // softmax: qq@S2 + sq@E0 contiguous (2BN rows), ss@E2 (BN rows)
  softmax_bf<<<dim3(2 * BN), blk, 0, stream>>>(U16(O_S2), inv_sqrt512);
  softmax_bf<<<dim3(BN), blk, 0, stream>>>(U16(O_E2), inv_sqrt512);
  // bindings: ass@E2, asq@E0, aqq@S2

  // ---- Phase B ----
  // merged K+Q batch32: z2=0 -> K = ass@Wk -> S1 ; z2=1 -> Q = asq@Wq -> S0
  gemm(1, U16(O_E2), Nn * Nn, -(long long)(2 * E2n), 1024,
       U16(O_WKT), 0, -(long long)(SZ_W1K / 2), 1024,
       U16(O_S1), Nn * 1024, -(long long)E2n, 1024,
       nullptr, 0, 1024, 1024, 1024, 32);
  // Vt[b][c][q] -> E1 (operand-swapped NT; asq@E0 dead after this + scores below)
  gemm(1, U16(O_WVT), 0, 0, 1024, U16(O_E0), Nn * Nn, 0, 1024, U16(O_E1), Nn * Nn, 0, 1024,
       nullptr, 0, 1024, 1024, 1024, (int)Bb);

  // attention scores batch32: z2=0 -> h0@E2 (ass dead), z2=1 -> h1@E0 (asq dead)
  gemm(1, U16(O_S0), Nn * 1024, 512, 1024, U16(O_S1), Nn * 1024, 512, 1024,
       U16(O_E2), Nn * Nn, -(long long)(2 * E2n), 1024, nullptr, 0, 1024, 1024, 512, 32);
  softmax_bf<<<dim3(BN), blk, 0, stream>>>(U16(O_E2), inv_sqrt512);
  softmax_bf<<<dim3(BN), blk, 0, stream>>>(U16(O_E0), inv_sqrt512);

  // o = attn @ V batch32 -> S0 (Q dead)
  gemm(1, U16(O_E2), Nn * Nn, -(long long)(2 * E2n), 1024,
       U16(O_E1), Nn * Nn, (long long)(512 * 1024), 1024,
       U16(O_S0), Nn * 1024, 512, 1024, nullptr, 0, 1024, 512, 1024, 32);

  // x = LN(o + aqq) -> bf16 -> S1 (K dead)
  ln1_k<<<dim3(BN), blk, 0, stream>>>(U16(O_S0), U16(O_S2), ln_g, ln_b, U16(O_S1));

  // h = relu(x @ ffn_w1) -> S2 (aqq dead)
  gemm(2, U16(O_S1), 0, 0, 1024, U16(O_F1T), 0, 0, 1024, U16(O_S2), 0, 0, 1024,
       nullptr, 0, (int)BN, 1024, 1024, 1);

  // y0 = h @ ffn_w2 + x -> f32 into d_out
  gemm(3, U16(O_S2), 0, 0, 1024, U16(O_F2T), 0, 0, 1024, out, 0, 0, 1024,
       U16(O_S1), 0, (int)BN, 1024, 1024, 1);

  // y = LN(y0) in place on d_out
  ln2_k<<<dim3(BN), blk, 0, stream>>>(out, fg, fb, out, 1e-6f);
}

// Round 9
// 710.439 us; speedup vs baseline: 1.0948x; 1.0948x over previous
//
#include <hip/hip_runtime.h>
#include <cstdint>

// ---------------- problem constants ----------------
static constexpr long long Bb = 16, Nn = 1024, FE = 512; // heads=2, g=512
static constexpr long long BN = Bb * Nn;        // 16384
static constexpr long long E1e = BN * FE;       // elems of [B,N,FE] (8388608)
static constexpr long long E2n = BN * Nn;       // elems of [B,N,N]

// ---------------- workspace layout (bytes) ----------------
static constexpr long long O_WT  = 0;                      // 6x 512x512 bf16 (plain cast W1..W6)
static constexpr long long SZ_W512 = FE * FE * 2;
static constexpr long long O_WQT = O_WT + 6 * SZ_W512;     // 1024-transposed weights
static constexpr long long SZ_W1K = Nn * Nn * 2;
static constexpr long long O_WKT = O_WQT + SZ_W1K;
static constexpr long long O_WVT = O_WKT + SZ_W1K;
static constexpr long long O_F1T = O_WVT + SZ_W1K;
static constexpr long long O_F2T = O_F1T + SZ_W1K;
static constexpr long long O_SLOTS = O_F2T + SZ_W1K;       // 13,631,488
static constexpr long long SLOT = E2n * 2;                 // 32 MiB
static constexpr long long O_S0 = O_SLOTS;                 // P planes -> Q -> o
static constexpr long long O_S1 = O_S0 + SLOT;             // P tail -> K -> x
static constexpr long long O_S2 = O_S1 + SLOT;             // Gt -> aqq -> h
static constexpr long long O_E0 = O_S2 + SLOT;             // F planes -> asq -> scores h1
static constexpr long long O_E1 = O_E0 + SLOT;             // Fq plane -> Vt
static constexpr long long O_E2 = O_E1 + SLOT;             // ass -> scores h0
static constexpr long long WS_NEED = O_E2 + SLOT;          // ~205 MiB
// phase-A temporaries:
static constexpr long long O_FB = O_E0;                    // F planes [Fms|Fs|Fq], stride E1e elems
static constexpr long long O_GT = O_S2;                    // 3x 512x512 Gt planes (dead after P)

// ---------------- helpers ----------------
typedef __attribute__((ext_vector_type(8))) short short8;
typedef __attribute__((ext_vector_type(4))) float f32x4;
typedef __attribute__((ext_vector_type(16))) float f32x16;

static __device__ __forceinline__ unsigned short f2bf(float f) {
  union { float f; unsigned u; } x; x.f = f;
  unsigned r = x.u + 0x7FFFu + ((x.u >> 16) & 1u);
  return (unsigned short)(r >> 16);
}
static __device__ __forceinline__ float bf2f(unsigned short h) {
  union { unsigned u; float f; } x; x.u = ((unsigned)h) << 16; return x.f;
}
static __device__ __forceinline__ void gload16(const void* g, void* l) {
  __builtin_amdgcn_global_load_lds(
      (const __attribute__((address_space(1))) unsigned int*)g,
      (__attribute__((address_space(3))) unsigned int*)l, 16, 0, 0);
}

// ============ CORE A (R6-verified): 16x16 MFMA, 2-phase K-step ==============
// C[m,n] = sum_k A[m,k]*B[n,k].  8 waves (2M x 4N), per-wave 128x64 out.
// BK=32; ring-4 x 32 KiB LDS; XOR swizzle slot s^((r>>1)&3); 0 bank conflicts
// measured.  vmcnt(8) counted; 2 barriers per phase.  (Round-6 core, 702us.)
template <int EP>
__global__ __launch_bounds__(512, 2) void gemm16(
    const unsigned short* __restrict__ A, long long sA, long long hA, int lda,
    const unsigned short* __restrict__ B, long long sB, long long hB, int ldb,
    void* __restrict__ Cv, long long sC, long long hC, int ldc,
    const void* __restrict__ Rv, long long sR, int K) {
  extern __shared__ unsigned short lds[];
  const int tid = threadIdx.x;
  const int lane = tid & 63;
  const int wave = tid >> 6;
  const int wm = wave >> 2, wn = wave & 3;
  const int lrow = lane & 15, quad = lane >> 4;

  const int gx = gridDim.x;
  const int nxy = gx * gridDim.y;
  const int nwg = nxy * gridDim.z;
  int wg = blockIdx.x + gx * blockIdx.y + nxy * blockIdx.z;
  {
    const int q = nwg >> 3, r = nwg & 7;
    const int xcd = wg & 7, blk = wg >> 3;
    wg = (xcd < r ? xcd * (q + 1) : r * (q + 1) + (xcd - r) * q) + blk;
  }
  const int bz = wg / nxy;
  const int rem = wg - bz * nxy;
  const int by = rem / gx;
  const int bx = rem - by * gx;
  const int z1 = bz & 15, z2 = bz >> 4;

  const long long bm = (long long)bx * 256;
  const long long bn = (long long)by * 256;
  const unsigned short* Ab = A + z1 * sA + z2 * hA + bm * lda;
  const unsigned short* Bp = B + z1 * sB + z2 * hB + bn * ldb;

  const int srow = tid >> 2;
  const int scol = ((tid & 3) ^ ((tid >> 3) & 3)) * 8;  // elems
  unsigned short* ldst = lds + tid * 8;

  const int swq = (quad ^ ((lrow >> 1) & 3)) * 8;
  const int a_off = (wm * 128 + lrow) * 32 + swq;
  const int b_off = 8192 + (wn * 64 + lrow) * 32 + swq;

  f32x4 acc[8][4];
#pragma unroll
  for (int m = 0; m < 8; ++m)
#pragma unroll
    for (int n = 0; n < 4; ++n) acc[m][n] = (f32x4){0.f, 0.f, 0.f, 0.f};

  short8 af[8], bfr[4];
  auto READ_A0 = [&](int tt) {
    const unsigned short* lb = lds + (tt & 3) * 16384;
    bfr[0] = *(const short8*)&lb[b_off + 0 * 512];
    bfr[1] = *(const short8*)&lb[b_off + 1 * 512];
    bfr[2] = *(const short8*)&lb[b_off + 2 * 512];
    bfr[3] = *(const short8*)&lb[b_off + 3 * 512];
#pragma unroll
    for (int m = 0; m < 4; ++m) af[m] = *(const short8*)&lb[a_off + m * 512];
  };
  auto READ_A1 = [&](int tt) {
    const unsigned short* lb = lds + (tt & 3) * 16384;
#pragma unroll
    for (int m = 4; m < 8; ++m) af[m] = *(const short8*)&lb[a_off + m * 512];
  };
  auto MFMA_H = [&](int m0) {
    __builtin_amdgcn_s_setprio(1);
#pragma unroll
    for (int m = m0; m < m0 + 4; ++m)
#pragma unroll
      for (int n = 0; n < 4; ++n)
        acc[m][n] = __builtin_amdgcn_mfma_f32_16x16x32_bf16(af[m], bfr[n], acc[m][n], 0, 0, 0);
    __builtin_amdgcn_s_setprio(0);
  };
  auto STAGE = [&](int tt) {
    unsigned short* d = ldst + (tt & 3) * 16384;
    const long long ko = (long long)tt * 32 + scol;
    gload16(Ab + (long long)srow * lda + ko, d);
    gload16(Ab + (long long)(srow + 128) * lda + ko, d + 4096);
    gload16(Bp + (long long)srow * ldb + ko, d + 8192);
    gload16(Bp + (long long)(srow + 128) * ldb + ko, d + 12288);
  };

  const int nt = K >> 5;
  STAGE(0); STAGE(1); STAGE(2);
  asm volatile("s_waitcnt vmcnt(8)" ::: "memory");
  __builtin_amdgcn_s_barrier();
  int t = 0;
  for (; t < nt - 3; ++t) {
    unsigned short* d = ldst + ((t + 3) & 3) * 16384;
    const long long ko = (long long)(t + 3) * 32 + scol;
    READ_A0(t);
    gload16(Ab + (long long)srow * lda + ko, d);
    gload16(Ab + (long long)(srow + 128) * lda + ko, d + 4096);
    __builtin_amdgcn_s_barrier();
    MFMA_H(0);
    __builtin_amdgcn_s_barrier();
    READ_A1(t);
    gload16(Bp + (long long)srow * ldb + ko, d + 8192);
    gload16(Bp + (long long)(srow + 128) * ldb + ko, d + 12288);
    asm volatile("s_waitcnt vmcnt(8)" ::: "memory");
    __builtin_amdgcn_s_barrier();
    MFMA_H(4);
    __builtin_amdgcn_s_barrier();
  }
  READ_A0(t);
  __builtin_amdgcn_s_barrier();
  MFMA_H(0);
  __builtin_amdgcn_s_barrier();
  READ_A1(t);
  asm volatile("s_waitcnt vmcnt(4)" ::: "memory");
  __builtin_amdgcn_s_barrier();
  MFMA_H(4);
  __builtin_amdgcn_s_barrier();
  ++t;
  READ_A0(t);
  __builtin_amdgcn_s_barrier();
  MFMA_H(0);
  __builtin_amdgcn_s_barrier();
  READ_A1(t);
  asm volatile("s_waitcnt vmcnt(0)" ::: "memory");
  __builtin_amdgcn_s_barrier();
  MFMA_H(4);
  __builtin_amdgcn_s_barrier();
  ++t;
  READ_A0(t);
  MFMA_H(0);
  READ_A1(t);
  MFMA_H(4);

  const long long cm = bm + wm * 128, cn = bn + wn * 64;
  const long long cz = z1 * sC + z2 * hC;
#pragma unroll
  for (int mt = 0; mt < 8; ++mt) {
#pragma unroll
    for (int ntl = 0; ntl < 4; ++ntl) {
      long long col = cn + ntl * 16 + lrow;
      long long row0 = cm + mt * 16 + quad * 4;
#pragma unroll
      for (int r = 0; r < 4; ++r) {
        long long row = row0 + r;
        float v = acc[mt][ntl][r];
        long long idx = cz + row * ldc + col;
        if (EP == 1) ((unsigned short*)Cv)[idx] = f2bf(v);
        else if (EP == 2) ((unsigned short*)Cv)[idx] = f2bf(v > 0.f ? v : 0.f);
        else {
          float rr = bf2f(((const unsigned short*)Rv)[z1 * sR + row * ldc + col]);
          ((float*)Cv)[idx] = v + rr;
        }
      }
    }
  }
}

// ============ CORE B (R7-verified): 32x32 MFMA, cross-slice pipeline ========
// Used ONLY for the K+Q dispatch (batch 32, M=N=K=1024) where it measured
// 73us vs core-A's 84us (MfmaUtil 41%).  Carries 4 conflict-counts per
// ds_read (unresolved counter source) but is net faster on this shape.
__global__ __launch_bounds__(512, 2) void gemm32(
    const unsigned short* __restrict__ A, long long sA, long long hA, int lda,
    const unsigned short* __restrict__ B, long long sB, long long hB, int ldb,
    void* __restrict__ Cv, long long sC, long long hC, int ldc, int K) {
  extern __shared__ unsigned short lds[];
  const int tid = threadIdx.x;
  const int lane = tid & 63;
  const int wave = tid >> 6;
  const int wm = wave >> 2, wn = wave & 3;
  const int l31 = lane & 31, lh = lane >> 5;

  const int gx = gridDim.x;
  const int nxy = gx * gridDim.y;
  const int nwg = nxy * gridDim.z;
  int wg = blockIdx.x + gx * blockIdx.y + nxy * blockIdx.z;
  {
    const int q = nwg >> 3, r = nwg & 7;
    const int xcd = wg & 7, blk = wg >> 3;
    wg = (xcd < r ? xcd * (q + 1) : r * (q + 1) + (xcd - r) * q) + blk;
  }
  const int bz = wg / nxy;
  const int rem = wg - bz * nxy;
  const int by = rem / gx;
  const int bx = rem - by * gx;
  const int z1 = bz & 15, z2 = bz >> 4;

  const long long bm = (long long)bx * 256;
  const long long bn = (long long)by * 256;
  const unsigned short* Ab = A + z1 * sA + z2 * hA + bm * lda;
  const unsigned short* Bp = B + z1 * sB + z2 * hB + bn * ldb;

  const int srow = tid >> 2;
  const int scol = ((tid & 3) ^ ((tid >> 3) & 3)) * 8;  // elems
  unsigned short* ldst = lds + tid * 8;
  auto STAGE = [&](int tt) {
    unsigned short* d = ldst + (tt & 3) * 16384;
    const long long ko = (long long)tt * 32 + scol;
    gload16(Ab + (long long)srow * lda + ko, d);
    gload16(Ab + (long long)(srow + 128) * lda + ko, d + 4096);
    gload16(Bp + (long long)srow * ldb + ko, d + 8192);
    gload16(Bp + (long long)(srow + 128) * ldb + ko, d + 12288);
  };

  const int swz = (l31 >> 1) & 3;
  const int arow = (wm * 128 + l31) * 32;
  const int brow = 8192 + (wn * 64 + l31) * 32;
  const int aoff0 = arow + ((0 + lh) ^ swz) * 8;
  const int aoff1 = arow + ((2 + lh) ^ swz) * 8;
  const int boff0 = brow + ((0 + lh) ^ swz) * 8;
  const int boff1 = brow + ((2 + lh) ^ swz) * 8;

  f32x16 acc[4][2];
#pragma unroll
  for (int mi = 0; mi < 4; ++mi)
#pragma unroll
    for (int ni = 0; ni < 2; ++ni)
      acc[mi][ni] = (f32x16){0.f, 0.f, 0.f, 0.f, 0.f, 0.f, 0.f, 0.f,
                             0.f, 0.f, 0.f, 0.f, 0.f, 0.f, 0.f, 0.f};

  short8 a0[4], b0[2], a1[4], b1[2];
  auto READ0 = [&](int tt) {
    const unsigned short* lb = lds + (tt & 3) * 16384;
#pragma unroll
    for (int mi = 0; mi < 4; ++mi) a0[mi] = *(const short8*)&lb[aoff0 + mi * 1024];
    b0[0] = *(const short8*)&lb[boff0];
    b0[1] = *(const short8*)&lb[boff0 + 1024];
  };
  auto READ1 = [&](int tt) {
    const unsigned short* lb = lds + (tt & 3) * 16384;
#pragma unroll
    for (int mi = 0; mi < 4; ++mi) a1[mi] = *(const short8*)&lb[aoff1 + mi * 1024];
    b1[0] = *(const short8*)&lb[boff1];
    b1[1] = *(const short8*)&lb[boff1 + 1024];
  };
  auto MFMA8 = [&](const short8* a, const short8* b) {
    __builtin_amdgcn_s_setprio(1);
#pragma unroll
    for (int mi = 0; mi < 4; ++mi)
#pragma unroll
      for (int ni = 0; ni < 2; ++ni)
        acc[mi][ni] = __builtin_amdgcn_mfma_f32_32x32x16_bf16(a[mi], b[ni], acc[mi][ni], 0, 0, 0);
    __builtin_amdgcn_s_setprio(0);
  };

  const int nt = K >> 5;
  STAGE(0); STAGE(1); STAGE(2);
  asm volatile("s_waitcnt vmcnt(8)" ::: "memory");
  __builtin_amdgcn_s_barrier();
  READ0(0);
  int t = 0;
  for (; t < nt - 3; ++t) {
    READ1(t);
    MFMA8(a0, b0);
    STAGE(t + 3);
    asm volatile("s_waitcnt vmcnt(8)" ::: "memory");
    asm volatile("s_waitcnt lgkmcnt(0)" ::: "memory");
    __builtin_amdgcn_s_barrier();
    READ0(t + 1);
    MFMA8(a1, b1);
  }
  READ1(t);
  MFMA8(a0, b0);
  asm volatile("s_waitcnt vmcnt(4)" ::: "memory");
  asm volatile("s_waitcnt lgkmcnt(0)" ::: "memory");
  __builtin_amdgcn_s_barrier();
  READ0(t + 1);
  MFMA8(a1, b1);
  ++t;
  READ1(t);
  MFMA8(a0, b0);
  asm volatile("s_waitcnt vmcnt(0)" ::: "memory");
  asm volatile("s_waitcnt lgkmcnt(0)" ::: "memory");
  __builtin_amdgcn_s_barrier();
  READ0(t + 1);
  MFMA8(a1, b1);
  ++t;
  READ1(t);
  MFMA8(a0, b0);
  MFMA8(a1, b1);

  const long long cm = bm + wm * 128, cn = bn + wn * 64;
  const long long cz = z1 * sC + z2 * hC;
#pragma unroll
  for (int mi = 0; mi < 4; ++mi) {
#pragma unroll
    for (int ni = 0; ni < 2; ++ni) {
      long long col = cn + ni * 32 + l31;
#pragma unroll
      for (int reg = 0; reg < 16; ++reg) {
        long long row = cm + mi * 32 + (reg & 3) + 8 * (reg >> 2) + 4 * lh;
        long long idx = cz + row * ldc + col;
        ((unsigned short*)Cv)[idx] = f2bf(acc[mi][ni][reg]);
      }
    }
  }
}

// ---------------- merged cast f32 -> bf16, 3 planes per dispatch ----------------
__global__ __launch_bounds__(256) void cast3_k(const float* __restrict__ i0,
                                               const float* __restrict__ i1,
                                               const float* __restrict__ i2,
                                               unsigned short* o0, unsigned short* o1,
                                               unsigned short* o2) {
  const float* in = (blockIdx.y == 0) ? i0 : (blockIdx.y == 1) ? i1 : i2;
  unsigned short* out = (blockIdx.y == 0) ? o0 : (blockIdx.y == 1) ? o1 : o2;
  long long i = (long long)blockIdx.x * 256 + threadIdx.x;
  float4 v = ((const float4*)in)[i];
  ushort4 o; o.x = f2bf(v.x); o.y = f2bf(v.y); o.z = f2bf(v.z); o.w = f2bf(v.w);
  ((ushort4*)out)[i] = o;
}

// ---------------- merged transpose+cast: z selects source ----------------
__global__ __launch_bounds__(256) void tcast6_k(const float* p0, const float* p1,
                                                const float* p2, const float* p3,
                                                const float* p4, const float* p5,
                                                unsigned short* outb, int rows, int cols) {
  const float* src[6] = {p0, p1, p2, p3, p4, p5};
  const float* in = src[blockIdx.z];
  unsigned short* out = outb + (long long)blockIdx.z * rows * cols;
  __shared__ float t[32][33];
  const int c0 = blockIdx.x * 32, r0 = blockIdx.y * 32;
  const int tx = threadIdx.x, ty = threadIdx.y; // block (32,8)
#pragma unroll
  for (int i = 0; i < 4; ++i) {
    int r = r0 + ty + i * 8;
    t[ty + i * 8][tx] = in[(long long)r * cols + c0 + tx];
  }
  __syncthreads();
#pragma unroll
  for (int i = 0; i < 4; ++i) {
    int c = c0 + ty + i * 8;
    out[(long long)c * rows + r0 + tx] = f2bf(t[tx][ty + i * 8]);
  }
}

// -------- in-place row softmax over bf16 (1024 cols), dual region ---------
// blocks [0,split) -> p0, [split,total) -> p1
__global__ __launch_bounds__(256) void softmax_dual(unsigned short* __restrict__ p0,
                                                    unsigned short* __restrict__ p1,
                                                    long long split, float scale) {
  __shared__ float redA[4], redB[4];
  const long long row = blockIdx.x;
  unsigned short* base = (row < split) ? (p0 + row * 1024) : (p1 + (row - split) * 1024);
  const int t = threadIdx.x, wave = t >> 6, lane = t & 63;
  ushort4 u = ((ushort4*)base)[t];
  float v0 = bf2f(u.x) * scale, v1 = bf2f(u.y) * scale, v2 = bf2f(u.z) * scale, v3 = bf2f(u.w) * scale;
  float m = fmaxf(fmaxf(v0, v1), fmaxf(v2, v3));
#pragma unroll
  for (int o = 32; o; o >>= 1) m = fmaxf(m, __shfl_down(m, o));
  if (lane == 0) redA[wave] = m;
  __syncthreads();
  m = fmaxf(fmaxf(redA[0], redA[1]), fmaxf(redA[2], redA[3]));
  float e0 = __expf(v0 - m), e1 = __expf(v1 - m), e2 = __expf(v2 - m), e3 = __expf(v3 - m);
  float s = e0 + e1 + e2 + e3;
#pragma unroll
  for (int o = 32; o; o >>= 1) s += __shfl_down(s, o);
  if (lane == 0) redB[wave] = s;
  __syncthreads();
  s = redB[0] + redB[1] + redB[2] + redB[3];
  float inv = 1.f / s;
  ushort4 ob; ob.x = f2bf(e0 * inv); ob.y = f2bf(e1 * inv); ob.z = f2bf(e2 * inv); ob.w = f2bf(e3 * inv);
  ((ushort4*)base)[t] = ob;
}

// ---------------- LN1: x = LN(o + aqq)*g + b -> bf16 ----------------
__global__ __launch_bounds__(256) void ln1_k(const unsigned short* __restrict__ O,
                                             const unsigned short* __restrict__ Aq,
                                             const float* __restrict__ g, const float* __restrict__ b,
                                             unsigned short* __restrict__ xb) {
  __shared__ float redA[4], redB[4];
  const long long row = blockIdx.x;
  const int t = threadIdx.x, wave = t >> 6, lane = t & 63;
  ushort4 ou = ((const ushort4*)(O + row * 1024))[t];
  ushort4 au = ((const ushort4*)(Aq + row * 1024))[t];
  float v0 = bf2f(ou.x) + bf2f(au.x), v1 = bf2f(ou.y) + bf2f(au.y);
  float v2 = bf2f(ou.z) + bf2f(au.z), v3 = bf2f(ou.w) + bf2f(au.w);
  float s = v0 + v1 + v2 + v3;
  float q = v0 * v0 + v1 * v1 + v2 * v2 + v3 * v3;
#pragma unroll
  for (int o = 32; o; o >>= 1) { s += __shfl_down(s, o); q += __shfl_down(q, o); }
  if (lane == 0) { redA[wave] = s; redB[wave] = q; }
  __syncthreads();
  float S = redA[0] + redA[1] + redA[2] + redA[3];
  float Q = redB[0] + redB[1] + redB[2] + redB[3];
  float mu = S * (1.f / 1024.f);
  float var = Q * (1.f / 1024.f) - mu * mu;
  float rs = rsqrtf(var + 1e-5f);
  float4 gg = ((const float4*)g)[t], bbv = ((const float4*)b)[t];
  ushort4 ob;
  ob.x = f2bf((v0 - mu) * rs * gg.x + bbv.x);
  ob.y = f2bf((v1 - mu) * rs * gg.y + bbv.y);
  ob.z = f2bf((v2 - mu) * rs * gg.z + bbv.z);
  ob.w = f2bf((v3 - mu) * rs * gg.w + bbv.w);
  ((ushort4*)(xb + row * 1024))[t] = ob;
}

// ---------------- LN2: y = LN(y0)*g + b, f32 in-place safe ----------------
__global__ __launch_bounds__(256) void ln2_k(const float* __restrict__ Y,
                                             const float* __restrict__ g, const float* __restrict__ b,
                                             float* __restrict__ out, float eps) {
  __shared__ float redA[4], redB[4];
  const long long row = blockIdx.x;
  const int t = threadIdx.x, wave = t >> 6, lane = t & 63;
  float4 v = ((const float4*)(Y + row * 1024))[t];
  float s = v.x + v.y + v.z + v.w;
  float q = v.x * v.x + v.y * v.y + v.z * v.z + v.w * v.w;
#pragma unroll
  for (int o = 32; o; o >>= 1) { s += __shfl_down(s, o); q += __shfl_down(q, o); }
  if (lane == 0) { redA[wave] = s; redB[wave] = q; }
  __syncthreads();
  float S = redA[0] + redA[1] + redA[2] + redA[3];
  float Q = redB[0] + redB[1] + redB[2] + redB[3];
  float mu = S * (1.f / 1024.f);
  float var = Q * (1.f / 1024.f) - mu * mu;
  float rs = rsqrtf(var + eps);
  float4 gg = ((const float4*)g)[t], bbv = ((const float4*)b)[t];
  float4 o;
  o.x = (v.x - mu) * rs * gg.x + bbv.x;
  o.y = (v.y - mu) * rs * gg.y + bbv.y;
  o.z = (v.z - mu) * rs * gg.z + bbv.z;
  o.w = (v.w - mu) * rs * gg.w + bbv.w;
  ((float4*)(out + row * 1024))[t] = o;
}

// ---------------- launcher ----------------
extern "C" void kernel_launch(void* const* d_in, const int* in_sizes, int n_in,
                              void* d_out, int out_size, void* d_ws, size_t ws_size,
                              hipStream_t stream) {
  (void)in_sizes; (void)n_in; (void)out_size;
  if (ws_size < (size_t)WS_NEED) return; // diagnostic guard (absmax ~7.09 if hit)

  static int attr_once = []() {
    (void)hipFuncSetAttribute(reinterpret_cast<const void*>(&gemm16<1>),
                              hipFuncAttributeMaxDynamicSharedMemorySize, 131072);
    (void)hipFuncSetAttribute(reinterpret_cast<const void*>(&gemm16<2>),
                              hipFuncAttributeMaxDynamicSharedMemorySize, 131072);
    (void)hipFuncSetAttribute(reinterpret_cast<const void*>(&gemm16<3>),
                              hipFuncAttributeMaxDynamicSharedMemorySize, 131072);
    (void)hipFuncSetAttribute(reinterpret_cast<const void*>(&gemm32),
                              hipFuncAttributeMaxDynamicSharedMemorySize, 131072);
    return 0;
  }();
  (void)attr_once;

  const float* Fs  = (const float*)d_in[0];
  const float* Fq  = (const float*)d_in[1];
  const float* Fms = (const float*)d_in[2];
  const float* Wm[6] = {(const float*)d_in[4], (const float*)d_in[5], (const float*)d_in[6],
                        (const float*)d_in[7], (const float*)d_in[8], (const float*)d_in[9]};
  const float* Wq = (const float*)d_in[10];
  const float* Wk = (const float*)d_in[11];
  const float* Wv = (const float*)d_in[12];
  const float* ln_g = (const float*)d_in[13];
  const float* ln_b = (const float*)d_in[14];
  const float* fw1 = (const float*)d_in[15];
  const float* fw2 = (const float*)d_in[16];
  const float* fg = (const float*)d_in[17];
  const float* fb = (const float*)d_in[18];
  float* out = (float*)d_out;
  uint8_t* ws = (uint8_t*)d_ws;
  auto U16 = [&](long long off) { return (unsigned short*)(ws + off); };

  const float inv_sqrt512 = 0.04419417382415922f; // 1/sqrt(512) == 1/sqrt(g)
  dim3 blk(256);

  auto gemm = [&](int ep, const unsigned short* A, long long sA, long long hA, int lda,
                  const unsigned short* B, long long sB, long long hB, int ldb,
                  void* C, long long sC, long long hC, int ldc, const void* R, long long sR,
                  int M, int N, int K, int batch) {
    dim3 g(M / 256, N / 256, batch);
    dim3 b(512);
    if (ep == 1 && batch == 32 && N == 1024 && K == 1024) {
      // K+Q dispatch: core B (32x32 pipelined), measured 73us vs 84us
      gemm32<<<g, b, 131072, stream>>>(A, sA, hA, lda, B, sB, hB, ldb, C, sC, hC, ldc, K);
      return;
    }
    switch (ep) {
      case 1: gemm16<1><<<g, b, 131072, stream>>>(A, sA, hA, lda, B, sB, hB, ldb, C, sC, hC, ldc, R, sR, K); break;
      case 2: gemm16<2><<<g, b, 131072, stream>>>(A, sA, hA, lda, B, sB, hB, ldb, C, sC, hC, ldc, R, sR, K); break;
      default: gemm16<3><<<g, b, 131072, stream>>>(A, sA, hA, lda, B, sB, hB, ldb, C, sC, hC, ldc, R, sR, K); break;
    }
  };

  // ---- weight prep ----
  unsigned short* Wc = U16(O_WT);
  cast3_k<<<dim3(256, 3), blk, 0, stream>>>(Wm[0], Wm[1], Wm[2], Wc, Wc + 262144, Wc + 2 * 262144);
  cast3_k<<<dim3(256, 3), blk, 0, stream>>>(Wm[3], Wm[4], Wm[5], Wc + 3 * 262144, Wc + 4 * 262144, Wc + 5 * 262144);
  tcast6_k<<<dim3(32, 32, 5), dim3(32, 8), 0, stream>>>(
      Wq, Wk, Wv, fw1, fw2, fw2 /*unused*/, U16(O_WQT), 1024, 1024);
  unsigned short* FB = U16(O_FB);
  cast3_k<<<dim3(E1e / 4 / 256, 3), blk, 0, stream>>>(
      Fms, Fs, Fq, FB, FB + E1e, FB + 2 * E1e);

  // ---- Phase A: affinities via fused weight products ----
  // Gt planes [ss,sq,qq]: Gt_xy = NT(W_even, W_odd)
  gemm(1, Wc + 262144, 524288, 0, 512, Wc, 524288, 0, 512,
       U16(O_GT), 262144, 0, 512, nullptr, 0, 512, 512, 512, 3);
  // P planes = NT(F, Gt) -> S0 (stride E1e)
  gemm(1, FB, E1e, 0, 512, U16(O_GT), 262144, 0, 512,
       U16(O_S0), E1e, 0, 512, nullptr, 0, (int)BN, 512, 512, 3);
  // scores_ss = NT(P_ss, Fms) batch16 -> E2
  gemm(1, U16(O_S0), Nn * 512, 0, 512, FB, Nn * 512, 0, 512,
       U16(O_E2), Nn * Nn, 0, 1024, nullptr, 0, 1024, 1024, 512, (int)Bb);
  // scores_sq/qq = NT(P_sq|P_qq, Fq) batch32: z2=0 -> sq@E0, z2=1 -> qq@S2
  gemm(1, U16(O_S0) + E1e, Nn * 512, E1e, 512, FB + 2 * E1e, Nn * 512, 0, 512,
       U16(O_E0), Nn * Nn, -(long long)E2n, 1024, nullptr, 0, 1024, 1024, 512, 32);
  // softmax all 3BN affinity rows: [S2|E0] contiguous 2BN + E2 BN
  softmax_dual<<<dim3(3 * BN), blk, 0, stream>>>(U16(O_S2), U16(O_E2), 2 * BN, inv_sqrt512);
  // bindings: ass@E2, asq@E0, aqq@S2

  // ---- Phase B ----
  // merged K+Q batch32 (core B): z2=0 -> K = ass@Wk -> S1 ; z2=1 -> Q = asq@Wq -> S0
  gemm(1, U16(O_E2), Nn * Nn, -(long long)(2 * E2n), 1024,
       U16(O_WKT), 0, -(long long)(SZ_W1K / 2), 1024,
       U16(O_S1), Nn * 1024, -(long long)E2n, 1024,
       nullptr, 0, 1024, 1024, 1024, 32);
  // Vt[b][c][q] -> E1 (operand-swapped NT)
  gemm(1, U16(O_WVT), 0, 0, 1024, U16(O_E0), Nn * Nn, 0, 1024, U16(O_E1), Nn * Nn, 0, 1024,
       nullptr, 0, 1024, 1024, 1024, (int)Bb);

  // attention scores batch32: z2=0 -> h0@E2 (ass dead), z2=1 -> h1@E0 (asq dead)
  gemm(1, U16(O_S0), Nn * 1024, 512, 1024, U16(O_S1), Nn * 1024, 512, 1024,
       U16(O_E2), Nn * Nn, -(long long)(2 * E2n), 1024, nullptr, 0, 1024, 1024, 512, 32);
  softmax_dual<<<dim3(2 * BN), blk, 0, stream>>>(U16(O_E2), U16(O_E0), BN, inv_sqrt512);

  // o = attn @ V batch32 -> S0 (Q dead)
  gemm(1, U16(O_E2), Nn * Nn, -(long long)(2 * E2n), 1024,
       U16(O_E1), Nn * Nn, (long long)(512 * 1024), 1024,
       U16(O_S0), Nn * 1024, 512, 1024, nullptr, 0, 1024, 512, 1024, 32);

  // x = LN(o + aqq) -> bf16 -> S1 (K dead)
  ln1_k<<<dim3(BN), blk, 0, stream>>>(U16(O_S0), U16(O_S2), ln_g, ln_b, U16(O_S1));

  // h = relu(x @ ffn_w1) -> S2 (aqq dead)
  gemm(2, U16(O_S1), 0, 0, 1024, U16(O_F1T), 0, 0, 1024, U16(O_S2), 0, 0, 1024,
       nullptr, 0, (int)BN, 1024, 1024, 1);

  // y0 = h @ ffn_w2 + x -> f32 into d_out
  gemm(3, U16(O_S2), 0, 0, 1024, U16(O_F2T), 0, 0, 1024, out, 0, 0, 1024,
       U16(O_S1), 0, (int)BN, 1024, 1024, 1);

  // y = LN(y0) in place on d_out
  ln2_k<<<dim3(BN), blk, 0, stream>>>(out, fg, fb, out, 1e-6f);
}